// Round 10
// baseline (189.018 us; speedup 1.0000x reference)
//
#include <hip/hip_runtime.h>

// Sinkhorn image loss — CONVOLUTION form. C is the radial pairwise distance
// on a 48x48 grid, so K = exp(-C/eps) = exp(-1.5047 * d_pixels): translation
// invariant, decays e^-1.5 per pixel -> truncating to a 33x33 window (R=16)
// is exact to f32 (tail ~1e-9 of rowsum). Every matvec K*v becomes a 33x33
// zero-padded convolution; K (21 MB) never touches memory. Weight table is
// built EXACTLY from C via reference pixel (24,24) (same-offset distances are
// bitwise identical in the input), so weights == exp(-100*C_ij) exactly.
//   p = softmax(logits); q = target+1e-8; a1 = p/(K*1);
//   b_t = q/(K a_t); a_{t+1} = p/(K b_t);  cost = mean_b sum q/(K a10)*(KC a10)
//
// Pass kernel: 256 blocks = 16 batches x 16 three-row slices; 256 thr.
// Apron (35 x 80, stride 84) + weights in LDS; lane owns a 4-aligned output
// strip: per tap-row 9x ds_read_b128 (v) + 9 (wt, broadcast) + 132 FMA ->
// VALU-bound. 4 waves split the 33 dy rows, combine via LDS. ~1 us/pass.

namespace {

constexpr int N    = 2304;   // 48*48
constexpr int B    = 16;
constexpr int NB   = N * B;
constexpr int R    = 16;     // window radius (exp(-25.6)=8e-12 at r=17)
constexpr int WIN  = 33;     // window size
constexpr int WPAD = 36;     // padded wt row (f32), 3 zero taps
constexpr int RPB  = 3;      // output rows per block
constexpr int AR   = RPB + 2 * R;  // 35 apron rows
constexpr int AC   = 80;     // apron cols (-16..63)
constexpr int AST  = 84;     // apron LDS row stride (f32, 16B-mult, !=0 mod 32)
constexpr int NOUT = RPB * 48;     // 144 outputs per block
constexpr int NSTR = NOUT / 4;     // 36 strips of 4 outputs

__device__ __forceinline__ float wave_sum(float v) {
#pragma unroll
    for (int off = 32; off >= 1; off >>= 1) v += __shfl_xor(v, off);
    return v;
}

// ---------------------------------------------------------------- setup ---
// 1 block: per-batch softmax stats (m, 1/sum), wt tables from C's reference
// pixel row, zero d_out.
__global__ __launch_bounds__(256) void sk_setup(const float* __restrict__ logits,
                                                const float* __restrict__ C,
                                                float* __restrict__ wtab,
                                                float* __restrict__ wct,
                                                float* __restrict__ smstat,
                                                float* __restrict__ out) {
    const int tid = threadIdx.x, w = tid >> 6, lane = tid & 63;

    for (int b = w; b < B; b += 4) {
        float xs[36];
        float m = -3.0e38f;
#pragma unroll
        for (int s = 0; s < 36; ++s) {
            xs[s] = logits[b * N + s * 64 + lane];
            m = fmaxf(m, xs[s]);
        }
#pragma unroll
        for (int off = 32; off >= 1; off >>= 1) m = fmaxf(m, __shfl_xor(m, off));
        float sum = 0.f;
#pragma unroll
        for (int s = 0; s < 36; ++s) sum += __expf(xs[s] - m);
        sum = wave_sum(sum);
        if (lane == 0) { smstat[2 * b] = m; smstat[2 * b + 1] = 1.f / sum; }
    }

    // ref pixel (24,24) -> i = 1176; offset (dy-16, dx-16) -> j in [8,40]^2
    for (int idx = tid; idx < WIN * WPAD; idx += 256) {
        const int dy = idx / WPAD, dx = idx % WPAD;
        float wv = 0.f, wc = 0.f;
        if (dx < WIN) {
            const float c = C[1176 * N + (8 + dy) * 48 + (8 + dx)];
            wv = __expf(c * -100.f);
            wc = wv * c;
        }
        wtab[idx] = wv;
        wct[idx]  = wc;
    }
    if (tid == 0) out[0] = 0.f;
}

// ----------------------------------------------------------- conv pass ----
// dst[b][o] = src(o) / (conv33(win_b))(o).  ONES: apron = in-range indicator
// (a1's rowsum).  QSRC: src = target+1e-8 else exp(logit-m)*inv.
template <bool QSRC, bool ONES>
__global__ __launch_bounds__(256) void sk_pass(const float* __restrict__ win,
                                               const float* __restrict__ srcb,
                                               const float* __restrict__ wtab,
                                               const float* __restrict__ smstat,
                                               float* __restrict__ dst) {
    __shared__ float  vl[AR * AST];
    __shared__ float  wtl[WIN * WPAD];
    __shared__ float4 part[4][NSTR];

    const int bid = blockIdx.x;
    const int b   = bid & 15;        // batch (bid%8 -> XCD: same-batch co-XCD)
    const int y0  = (bid >> 4) * RPB;
    const int tid = threadIdx.x, w = tid >> 6, lane = tid & 63;

    for (int i = tid; i < WIN * WPAD; i += 256) wtl[i] = wtab[i];
    for (int i = tid; i < AR * AC; i += 256) {
        const int rr = i / AC, cc = i % AC;
        const int y = y0 - R + rr, x = cc - R;
        float v = 0.f;
        if ((unsigned)y < 48u && (unsigned)x < 48u)
            v = ONES ? 1.f : win[b * N + y * 48 + x];
        vl[rr * AST + cc] = v;
    }
    __syncthreads();

    // wave w -> dy in [8w, 8w+ndy); lane -> strip (row, 4-col group)
    const int dy0 = w * 8, ndy = (w == 3) ? 9 : 8;
    const int st = lane;
    float acc[4] = {0.f, 0.f, 0.f, 0.f};
    if (st < NSTR) {
        const int srow = st / 12, sx0 = (st % 12) * 4;
        for (int d = 0; d < ndy; ++d) {
            const int dy = dy0 + d;
            const float* vrow = &vl[(srow + dy) * AST + sx0];
            const float* wrow = &wtl[dy * WPAD];
            float vr[36], wr[36];
#pragma unroll
            for (int c = 0; c < 9; ++c) {
                *(float4*)&vr[4 * c] = *(const float4*)&vrow[4 * c];
                *(float4*)&wr[4 * c] = *(const float4*)&wrow[4 * c];
            }
#pragma unroll
            for (int kx = 0; kx < 4; ++kx) {
                float a = 0.f;
#pragma unroll
                for (int dx = 0; dx < 33; ++dx) a = fmaf(wr[dx], vr[kx + dx], a);
                acc[kx] += a;
            }
        }
        part[w][st] = make_float4(acc[0], acc[1], acc[2], acc[3]);
    }
    __syncthreads();

    if (tid < NOUT) {
        const float* pp = &part[0][0].x;   // flat [w][144]: idx st*4+kx == o
        const float s = pp[tid] + pp[NOUT + tid] + pp[2 * NOUT + tid] +
                        pp[3 * NOUT + tid];
        const int o = b * N + (y0 + tid / 48) * 48 + (tid % 48);
        float sv;
        if (QSRC) sv = srcb[o] + 1e-8f;
        else      sv = __expf(srcb[o] - smstat[2 * b]) * smstat[2 * b + 1];
        dst[o] = sv / s;
    }
}

// ---------------------------------------------------------------- cost ----
// s1 = (K a10), s2 = (K.C a10) via two convs sharing the apron; contribution
// q/s1*s2 over this block's 144 outputs; atomicAdd(out, sum/16).
__global__ __launch_bounds__(256) void sk_cost(const float* __restrict__ A,
                                               const float* __restrict__ target,
                                               const float* __restrict__ wtab,
                                               const float* __restrict__ wct,
                                               float* __restrict__ out) {
    __shared__ float  vl[AR * AST];
    __shared__ float  wtl[WIN * WPAD], wcl[WIN * WPAD];
    __shared__ float4 p1[4][NSTR], p2[4][NSTR];
    __shared__ float  wsum[4];

    const int bid = blockIdx.x;
    const int b   = bid & 15;
    const int y0  = (bid >> 4) * RPB;
    const int tid = threadIdx.x, w = tid >> 6, lane = tid & 63;

    for (int i = tid; i < WIN * WPAD; i += 256) {
        wtl[i] = wtab[i];
        wcl[i] = wct[i];
    }
    for (int i = tid; i < AR * AC; i += 256) {
        const int rr = i / AC, cc = i % AC;
        const int y = y0 - R + rr, x = cc - R;
        float v = 0.f;
        if ((unsigned)y < 48u && (unsigned)x < 48u) v = A[b * N + y * 48 + x];
        vl[rr * AST + cc] = v;
    }
    __syncthreads();

    const int dy0 = w * 8, ndy = (w == 3) ? 9 : 8;
    const int st = lane;
    float a1[4] = {0.f, 0.f, 0.f, 0.f}, a2[4] = {0.f, 0.f, 0.f, 0.f};
    if (st < NSTR) {
        const int srow = st / 12, sx0 = (st % 12) * 4;
        for (int d = 0; d < ndy; ++d) {
            const int dy = dy0 + d;
            const float* vrow = &vl[(srow + dy) * AST + sx0];
            float vr[36], wr[36], cr[36];
#pragma unroll
            for (int c = 0; c < 9; ++c) {
                *(float4*)&vr[4 * c] = *(const float4*)&vrow[4 * c];
                *(float4*)&wr[4 * c] = *(const float4*)&wtl[dy * WPAD + 4 * c];
                *(float4*)&cr[4 * c] = *(const float4*)&wcl[dy * WPAD + 4 * c];
            }
#pragma unroll
            for (int kx = 0; kx < 4; ++kx) {
                float s1 = 0.f, s2 = 0.f;
#pragma unroll
                for (int dx = 0; dx < 33; ++dx) {
                    s1 = fmaf(wr[dx], vr[kx + dx], s1);
                    s2 = fmaf(cr[dx], vr[kx + dx], s2);
                }
                a1[kx] += s1;
                a2[kx] += s2;
            }
        }
        p1[w][st] = make_float4(a1[0], a1[1], a1[2], a1[3]);
        p2[w][st] = make_float4(a2[0], a2[1], a2[2], a2[3]);
    }
    __syncthreads();

    float val = 0.f;
    if (tid < NOUT) {
        const float* q1 = &p1[0][0].x;
        const float* q2 = &p2[0][0].x;
        const float s1 = q1[tid] + q1[NOUT + tid] + q1[2 * NOUT + tid] +
                         q1[3 * NOUT + tid];
        const float s2 = q2[tid] + q2[NOUT + tid] + q2[2 * NOUT + tid] +
                         q2[3 * NOUT + tid];
        const int o = b * N + (y0 + tid / 48) * 48 + (tid % 48);
        val = (target[o] + 1e-8f) / s1 * s2;
    }
    val = wave_sum(val);
    if (lane == 0) wsum[w] = val;
    __syncthreads();
    if (tid == 0)
        atomicAdd(out, (wsum[0] + wsum[1] + wsum[2] + wsum[3]) * (1.f / 16.f));
}

}  // namespace

extern "C" void kernel_launch(void* const* d_in, const int* in_sizes, int n_in,
                              void* d_out, int out_size, void* d_ws, size_t ws_size,
                              hipStream_t stream) {
    const float* logits = (const float*)d_in[0];   // (B, 48, 48)
    const float* target = (const float*)d_in[1];   // (B, 48, 48)
    const float* C      = (const float*)d_in[2];   // (1, N, N)
    float* out = (float*)d_out;
    float* ws  = (float*)d_ws;

    float* wtab   = ws;                    // [33*36]
    float* wct    = wtab + WIN * WPAD;     // [33*36]
    float* smstat = wct + WIN * WPAD;      // [32]
    float* A      = smstat + 32;           // [B][N]
    float* Bh     = A + NB;                // [B][N]

    sk_setup<<<1, 256, 0, stream>>>(logits, C, wtab, wct, smstat, out);

    // a1 = p / rowsum(K)  (ones-conv)
    sk_pass<false, true><<<256, 256, 0, stream>>>(A, logits, wtab, smstat, A);

    // b1..b9, a2..a10 (b10 fused into cost)
    for (int t = 1; t <= 9; ++t) {
        sk_pass<true,  false><<<256, 256, 0, stream>>>(A,  target, wtab, smstat, Bh);
        sk_pass<false, false><<<256, 256, 0, stream>>>(Bh, logits, wtab, smstat, A);
    }

    sk_cost<<<256, 256, 0, stream>>>(A, target, wtab, wct, out);
}